// Round 1
// baseline (105.775 us; speedup 1.0000x reference)
//
#include <hip/hip_runtime.h>
#include <hip/hip_bf16.h>

#define B_   4
#define C_   64
#define N_   16384
#define K_   20
#define S_   10
#define OUT_ 64
#define CH_  128
#define ROWS_ (B_ * N_)

typedef __attribute__((ext_vector_type(4))) float  f32x4;
typedef __attribute__((ext_vector_type(8))) __bf16 bf16x8;
typedef __attribute__((ext_vector_type(4))) __bf16 bf16x4;

// ---------------- transpose (B,C,N) -> (B*N, C) ----------------
__global__ void k_transpose(const float* __restrict__ x, float* __restrict__ xt) {
  __shared__ float tile[32][33];
  const int b  = blockIdx.z;
  const int n0 = blockIdx.x * 32;
  const int c0 = blockIdx.y * 32;
  const int tx = threadIdx.x, ty = threadIdx.y;
#pragma unroll
  for (int k = 0; k < 32; k += 8)
    tile[ty + k][tx] = x[((size_t)(b * C_ + c0 + ty + k)) * N_ + n0 + tx];
  __syncthreads();
#pragma unroll
  for (int k = 0; k < 32; k += 8)
    xt[((size_t)(b * N_ + n0 + ty + k)) * C_ + c0 + tx] = tile[tx][ty + k];
}

// ---------------- stable top-S sample selection ----------------
__global__ void k_sample(const float* __restrict__ scores, const int* __restrict__ idxmat,
                         int* __restrict__ sampled) {
  const int j = blockIdx.x * 256 + threadIdx.x;
  if (j >= ROWS_) return;
  const float* sc = scores + (size_t)j * K_;
  const int*   id = idxmat + (size_t)j * K_;
  float sv[K_]; int iv[K_];
#pragma unroll
  for (int k = 0; k < K_; ++k) { sv[k] = sc[k]; iv[k] = id[k]; }
  int* outp = sampled + (size_t)j * S_;
#pragma unroll
  for (int k = 0; k < K_; ++k) {
    const float sk = sv[k];
    int rank = 0;
#pragma unroll
    for (int m = 0; m < K_; ++m)
      rank += ((sv[m] > sk) || (sv[m] == sk && m < k)) ? 1 : 0;
    if (rank < S_) outp[rank] = iv[k];
  }
}

// ---------------- BN stats: per-channel sums ----------------
// stats layout: [0:64)=sum_d  [64:128)=sumsq_d  [128:192)=sum_cen  [192:256)=sumsq_cen
__global__ void k_stats(const float* __restrict__ xt, const int* __restrict__ sampled,
                        float* __restrict__ stats) {
  const int lane = threadIdx.x & 63;
  const int wid  = blockIdx.x * (blockDim.x >> 6) + (threadIdx.x >> 6);
  const int nw   = gridDim.x * (blockDim.x >> 6);
  float sum_d = 0.f, sq_d = 0.f, sum_c = 0.f, sq_c = 0.f;
  for (int j = wid; j < ROWS_; j += nw) {
    const float cen = xt[(size_t)j * C_ + lane];
    sum_c += cen; sq_c += cen * cen;
    const int* sp = sampled + (size_t)j * S_;
#pragma unroll
    for (int s = 0; s < S_; ++s) {
      const int nb = sp[s];
      const float v = xt[(size_t)nb * C_ + lane];
      const float d = v - cen;
      sum_d += d; sq_d += d * d;
    }
  }
  __shared__ float red[4][256];
  const int t = threadIdx.x;
  red[0][t] = sum_d; red[1][t] = sq_d; red[2][t] = sum_c; red[3][t] = sq_c;
  __syncthreads();
  if (t < 64) {
#pragma unroll
    for (int qq = 0; qq < 4; ++qq) {
      float v = red[qq][t] + red[qq][t + 64] + red[qq][t + 128] + red[qq][t + 192];
      atomicAdd(&stats[qq * 64 + t], v);
    }
  }
}

// ---------------- fold BN into per-channel affine A,B ----------------
__global__ void k_finalize(const float* __restrict__ stats, const float* __restrict__ dww,
                           const float* __restrict__ gamma, const float* __restrict__ beta,
                           float* __restrict__ AB) {
  const int c = threadIdx.x;
  if (c >= CH_) return;
  float mean_e, var_e;
  if (c < C_) {
    const float cnt = (float)ROWS_ * (float)S_;
    const float su = stats[c], sq = stats[64 + c];
    mean_e = su / cnt;
    var_e  = sq / cnt - mean_e * mean_e;
  } else {
    const float cnt = (float)ROWS_;  // central repeats S times: mean/var == per-row mean/var
    const float su = stats[128 + (c - C_)], sq = stats[192 + (c - C_)];
    mean_e = su / cnt;
    var_e  = sq / cnt - mean_e * mean_e;
  }
  const float w = dww[c];
  const float g = gamma[c];
  const float inv = rsqrtf(w * w * var_e + 1e-5f);
  AB[c]       = w * g * inv;
  AB[CH_ + c] = beta[c] - w * mean_e * inv * g;
}

// ---------------- main: act + pointwise MFMA + max over S ----------------
__global__ __launch_bounds__(256) void k_main(
    const float* __restrict__ xt, const int* __restrict__ sampled,
    const float* __restrict__ AB, const float* __restrict__ pw,
    float* __restrict__ out) {
  __shared__ float  cen[16][68];        // central features (padded); reused for output staging
  __shared__ __bf16 act[16 * 128];      // XOR-swizzled act tile (rows of 256B)
  __shared__ int    nbl[16 * S_];

  const int t    = threadIdx.x;
  const int lane = t & 63;
  const int w    = t >> 6;              // wave 0..3 -> output cols [16w,16w+16)
  const int j0   = blockIdx.x * 16;
  const int b    = j0 / N_;
  const int n0   = j0 % N_;
  const int r    = t >> 4;              // row 0..15
  const int q    = t & 15;              // channel quad 0..15

  if (t < 16 * S_) nbl[t] = sampled[(size_t)j0 * S_ + t];

  const f32x4 a_d = *(const f32x4*)&AB[4 * q];
  const f32x4 a_c = *(const f32x4*)&AB[C_ + 4 * q];
  const f32x4 b_d = *(const f32x4*)&AB[CH_ + 4 * q];
  const f32x4 b_c = *(const f32x4*)&AB[CH_ + C_ + 4 * q];

  { // central features + act for channels [64,128) (s-invariant)
    f32x4 v = *(const f32x4*)&xt[(size_t)(j0 + r) * C_ + 4 * q];
    *(f32x4*)&cen[r][4 * q] = v;
    bf16x4 p;
#pragma unroll
    for (int i = 0; i < 4; ++i) {
      const float tt = a_c[i] * v[i] + b_c[i];
      const float av = fmaxf(tt, 0.2f * tt);   // leaky relu
      p[i] = (__bf16)av;
    }
    const int byt = r * 256 + (((C_ + 4 * q) * 2) ^ ((r & 7) << 4));
    *(bf16x4*)((char*)act + byt) = p;
  }

  // pw^T B-fragments in registers: wave w owns outputs 16w..16w+15
  bf16x8 bf[4];
  {
    const int o  = 16 * w + (lane & 15);
    const int kb = 8 * (lane >> 4);
#pragma unroll
    for (int ts = 0; ts < 4; ++ts) {
      const int k = 32 * ts + kb;
      f32x4 v0 = *(const f32x4*)&pw[(size_t)o * CH_ + k];
      f32x4 v1 = *(const f32x4*)&pw[(size_t)o * CH_ + k + 4];
      bf16x8 f;
#pragma unroll
      for (int i = 0; i < 4; ++i) { f[i] = (__bf16)v0[i]; f[4 + i] = (__bf16)v1[i]; }
      bf[ts] = f;
    }
  }

  f32x4 rmax;
  rmax[0] = rmax[1] = rmax[2] = rmax[3] = -__builtin_inff();

  __syncthreads();

  const int arow  = lane & 15;
  const int abase = arow * 256;
  const int aswz  = (arow & 7) << 4;
  const int akoff = 16 * (lane >> 4);   // byte offset of this lane's 8 bf16 within K-step

  for (int s = 0; s < S_; ++s) {
    // gather 16 neighbor rows; compute d-part act channels [0,64)
    const int nb = nbl[r * S_ + s];
    f32x4 v = *(const f32x4*)&xt[(size_t)nb * C_ + 4 * q];
    bf16x4 p;
#pragma unroll
    for (int i = 0; i < 4; ++i) {
      const float d  = v[i] - cen[r][4 * q + i];
      const float tt = a_d[i] * d + b_d[i];
      const float av = fmaxf(tt, 0.2f * tt);
      p[i] = (__bf16)av;
    }
    const int byt = r * 256 + ((8 * q) ^ ((r & 7) << 4));
    *(bf16x4*)((char*)act + byt) = p;
    __syncthreads();

    f32x4 acc = {0.f, 0.f, 0.f, 0.f};
#pragma unroll
    for (int ts = 0; ts < 4; ++ts) {
      const int byt2 = abase + ((64 * ts + akoff) ^ aswz);
      bf16x8 a = *(bf16x8*)((char*)act + byt2);
      acc = __builtin_amdgcn_mfma_f32_16x16x32_bf16(a, bf[ts], acc, 0, 0, 0);
    }
#pragma unroll
    for (int i = 0; i < 4; ++i) rmax[i] = fmaxf(rmax[i], acc[i]);
    __syncthreads();
  }

  { // stage running max into cen[][] (16 rows x 64 outs); C/D: col=lane&15, row=4*(lane>>4)+i
    const int ol = lane & 15;
    const int rb = 4 * (lane >> 4);
#pragma unroll
    for (int i = 0; i < 4; ++i) cen[rb + i][16 * w + ol] = rmax[i];
  }
  __syncthreads();
  { // coalesced store: out[b][o][n0..n0+15]
    const int o  = t >> 2;
    const int sg = t & 3;
    f32x4 v;
#pragma unroll
    for (int i = 0; i < 4; ++i) v[i] = cen[sg * 4 + i][o];
    *(f32x4*)&out[((size_t)(b * OUT_ + o)) * N_ + n0 + sg * 4] = v;
  }
}

extern "C" void kernel_launch(void* const* d_in, const int* in_sizes, int n_in,
                              void* d_out, int out_size, void* d_ws, size_t ws_size,
                              hipStream_t stream) {
  const float* x      = (const float*)d_in[0];
  const int*   cif    = (const int*)  d_in[1];
  const float* scores = (const float*)d_in[2];
  const float* dww    = (const float*)d_in[3];
  const float* pw     = (const float*)d_in[4];
  const float* gamma  = (const float*)d_in[5];
  const float* beta   = (const float*)d_in[6];
  float* out = (float*)d_out;

  char* ws = (char*)d_ws;
  float* xt      = (float*)(ws);                                  // 16,777,216 B
  int*   sampled = (int*)  (ws + 16777216);                       //  2,621,440 B
  float* stats   = (float*)(ws + 16777216 + 2621440);             //      1,024 B
  float* AB      = (float*)(ws + 16777216 + 2621440 + 1024);      //      1,024 B

  hipMemsetAsync(stats, 0, 256 * sizeof(float), stream);

  dim3 tb(32, 8);
  dim3 tg(N_ / 32, C_ / 32, B_);
  k_transpose<<<tg, tb, 0, stream>>>(x, xt);
  k_sample<<<ROWS_ / 256, 256, 0, stream>>>(scores, cif, sampled);
  k_stats<<<512, 256, 0, stream>>>(xt, sampled, stats);
  k_finalize<<<1, 128, 0, stream>>>(stats, dww, gamma, beta, AB);
  k_main<<<ROWS_ / 16, 256, 0, stream>>>(xt, sampled, AB, pw, out);
}

// Round 2
// 89.732 us; speedup vs baseline: 1.1788x; 1.1788x over previous
//
#include <hip/hip_runtime.h>
#include <hip/hip_bf16.h>

#define B_   4
#define C_   64
#define N_   16384
#define K_   20
#define S_   10
#define OUT_ 64
#define CH_  128
#define ROWS_ (B_ * N_)

typedef __attribute__((ext_vector_type(4))) float  f32x4;
typedef __attribute__((ext_vector_type(8))) __bf16 bf16x8;
typedef __attribute__((ext_vector_type(4))) __bf16 bf16x4;
typedef __attribute__((ext_vector_type(4))) unsigned short u16x4;

__device__ inline float bf2f(unsigned short u) {
  union { unsigned int i; float f; } x; x.i = ((unsigned int)u) << 16; return x.f;
}
__device__ inline float bflo(unsigned int u) {
  union { unsigned int i; float f; } x; x.i = u << 16; return x.f;
}
__device__ inline float bfhi(unsigned int u) {
  union { unsigned int i; float f; } x; x.i = u & 0xffff0000u; return x.f;
}

// ---------------- transpose (B,C,N) f32 -> (B*N, C) bf16 ----------------
__global__ void k_transpose(const float* __restrict__ x, __bf16* __restrict__ xt) {
  __shared__ float tile[32][33];   // [c_local][n_local]
  const int b  = blockIdx.z;
  const int n0 = blockIdx.x * 32;
  const int c0 = blockIdx.y * 32;
  const int tx = threadIdx.x, ty = threadIdx.y;
#pragma unroll
  for (int k = 0; k < 32; k += 8)
    tile[ty + k][tx] = x[((size_t)(b * C_ + c0 + ty + k)) * N_ + n0 + tx];
  __syncthreads();
  const int tid = ty * 32 + tx;
  const int nl = tid >> 3;          // 0..31 row (n)
  const int cb = (tid & 7) * 4;     // 0..28 channel block
  bf16x4 p;
#pragma unroll
  for (int i = 0; i < 4; ++i) p[i] = (__bf16)tile[cb + i][nl];
  *(bf16x4*)&xt[((size_t)(b * N_ + n0 + nl)) * C_ + c0 + cb] = p;
}

// ---------------- stable top-S sample selection ----------------
__global__ void k_sample(const float* __restrict__ scores, const int* __restrict__ idxmat,
                         int* __restrict__ sampled) {
  const int j = blockIdx.x * 256 + threadIdx.x;
  if (j >= ROWS_) return;
  const float* sc = scores + (size_t)j * K_;
  const int*   id = idxmat + (size_t)j * K_;
  float sv[K_]; int iv[K_];
#pragma unroll
  for (int k = 0; k < K_; ++k) { sv[k] = sc[k]; iv[k] = id[k]; }
  int* outp = sampled + (size_t)j * S_;
#pragma unroll
  for (int k = 0; k < K_; ++k) {
    const float sk = sv[k];
    int rank = 0;
#pragma unroll
    for (int m = 0; m < K_; ++m)
      rank += ((sv[m] > sk) || (sv[m] == sk && m < k)) ? 1 : 0;
    if (rank < S_) outp[rank] = iv[k];
  }
}

// ---------------- BN stats: per-channel sums (bf16 xt) ----------------
// stats: [0:64)=sum_d  [64:128)=sumsq_d  [128:192)=sum_cen  [192:256)=sumsq_cen
__global__ __launch_bounds__(256) void k_stats(const unsigned int* __restrict__ xtu,
                                               const int* __restrict__ sampled,
                                               float* __restrict__ stats) {
  const int t    = threadIdx.x;
  const int half = (blockIdx.x * 256 + t) >> 5;   // global half-wave id
  const int cp   = t & 31;                        // channel pair 0..31
  const int nh   = gridDim.x * 8;
  float sd0 = 0, sd1 = 0, qd0 = 0, qd1 = 0, sc0 = 0, sc1 = 0, qc0 = 0, qc1 = 0;
  for (int j = half; j < ROWS_; j += nh) {
    const unsigned int cu = xtu[(size_t)j * 32 + cp];
    const float c0 = bflo(cu), c1 = bfhi(cu);
    sc0 += c0; sc1 += c1; qc0 += c0 * c0; qc1 += c1 * c1;
    const int* sp = sampled + (size_t)j * S_;
#pragma unroll
    for (int s = 0; s < S_; ++s) {
      const int nb = sp[s];
      const unsigned int vu = xtu[(size_t)nb * 32 + cp];
      const float d0 = bflo(vu) - c0;
      const float d1 = bfhi(vu) - c1;
      sd0 += d0; qd0 += d0 * d0; sd1 += d1; qd1 += d1 * d1;
    }
  }
  __shared__ float sred[256];
  sred[t] = 0.f;
  __syncthreads();
  const int c0i = 2 * cp;
  atomicAdd(&sred[c0i], sd0);        atomicAdd(&sred[c0i + 1], sd1);
  atomicAdd(&sred[64 + c0i], qd0);   atomicAdd(&sred[64 + c0i + 1], qd1);
  atomicAdd(&sred[128 + c0i], sc0);  atomicAdd(&sred[128 + c0i + 1], sc1);
  atomicAdd(&sred[192 + c0i], qc0);  atomicAdd(&sred[192 + c0i + 1], qc1);
  __syncthreads();
  atomicAdd(&stats[t], sred[t]);
}

// ---------------- fold BN into per-channel affine A,B ----------------
__global__ void k_finalize(const float* __restrict__ stats, const float* __restrict__ dww,
                           const float* __restrict__ gamma, const float* __restrict__ beta,
                           float* __restrict__ AB) {
  const int c = threadIdx.x;
  if (c >= CH_) return;
  float mean_e, var_e;
  if (c < C_) {
    const float cnt = (float)ROWS_ * (float)S_;
    const float su = stats[c], sq = stats[64 + c];
    mean_e = su / cnt;
    var_e  = sq / cnt - mean_e * mean_e;
  } else {
    const float cnt = (float)ROWS_;
    const float su = stats[128 + (c - C_)], sq = stats[192 + (c - C_)];
    mean_e = su / cnt;
    var_e  = sq / cnt - mean_e * mean_e;
  }
  const float w = dww[c];
  const float g = gamma[c];
  const float inv = rsqrtf(w * w * var_e + 1e-5f);
  AB[c]       = w * g * inv;
  AB[CH_ + c] = beta[c] - w * mean_e * inv * g;
}

// ---------------- main: act + split pointwise MFMA + max over S ----------------
__global__ __launch_bounds__(256) void k_main(
    const __bf16* __restrict__ xt, const int* __restrict__ sampled,
    const float* __restrict__ AB, const float* __restrict__ pw,
    float* __restrict__ out) {
  __shared__ __bf16 dact[160 * 64];   // rows (s*16+r), 128B each, XOR-swizzled
  __shared__ __bf16 cact[16 * 64];    // central act rows
  __shared__ float  ost[16][68];      // output staging

  const int t    = threadIdx.x;
  const int lane = t & 63;
  const int w    = t >> 6;            // wave -> output cols [16w,16w+16)
  const int j0   = blockIdx.x * 16;
  const int b    = j0 / N_;
  const int n0   = j0 % N_;
  const int r    = t >> 4;            // row 0..15
  const int q    = t & 15;            // channel quad

  const f32x4 a_d = *(const f32x4*)&AB[4 * q];
  const f32x4 a_c = *(const f32x4*)&AB[C_ + 4 * q];
  const f32x4 b_d = *(const f32x4*)&AB[CH_ + 4 * q];
  const f32x4 b_c = *(const f32x4*)&AB[CH_ + C_ + 4 * q];

  // central load + c-act (channels 64..127 of edge)
  float cen[4];
  {
    u16x4 cu = *(const u16x4*)&xt[(size_t)(j0 + r) * C_ + 4 * q];
    bf16x4 p;
#pragma unroll
    for (int i = 0; i < 4; ++i) {
      cen[i] = bf2f(cu[i]);
      const float tt = a_c[i] * cen[i] + b_c[i];
      p[i] = (__bf16)fmaxf(tt, 0.2f * tt);
    }
    const int byt = r * 128 + ((8 * q) ^ ((r & 7) << 4));
    *(bf16x4*)((char*)cact + byt) = p;
  }

  // all S neighbor gathers + d-act (channels 0..63 of edge)
  const int* sp = sampled + (size_t)(j0 + r) * S_;
#pragma unroll
  for (int s = 0; s < S_; ++s) {
    const int nb = sp[s];
    u16x4 vu = *(const u16x4*)&xt[(size_t)nb * C_ + 4 * q];
    bf16x4 p;
#pragma unroll
    for (int i = 0; i < 4; ++i) {
      const float d  = bf2f(vu[i]) - cen[i];
      const float tt = a_d[i] * d + b_d[i];
      p[i] = (__bf16)fmaxf(tt, 0.2f * tt);
    }
    const int row = s * 16 + r;
    const int byt = row * 128 + ((8 * q) ^ ((r & 7) << 4));  // (row&7)==(r&7)
    *(bf16x4*)((char*)dact + byt) = p;
  }

  // B-fragments: pw^T; d-part K=[0,64), c-part K=[64,128)
  bf16x8 bfd[2], bfc[2];
  {
    const int o  = 16 * w + (lane & 15);
    const int kb = 8 * (lane >> 4);
#pragma unroll
    for (int ts = 0; ts < 2; ++ts) {
      const int k = 32 * ts + kb;
      f32x4 v0 = *(const f32x4*)&pw[(size_t)o * CH_ + k];
      f32x4 v1 = *(const f32x4*)&pw[(size_t)o * CH_ + k + 4];
      f32x4 w0 = *(const f32x4*)&pw[(size_t)o * CH_ + C_ + k];
      f32x4 w1 = *(const f32x4*)&pw[(size_t)o * CH_ + C_ + k + 4];
      bf16x8 f, g;
#pragma unroll
      for (int i = 0; i < 4; ++i) {
        f[i] = (__bf16)v0[i]; f[4 + i] = (__bf16)v1[i];
        g[i] = (__bf16)w0[i]; g[4 + i] = (__bf16)w1[i];
      }
      bfd[ts] = f; bfc[ts] = g;
    }
  }

  __syncthreads();

  const int arow  = lane & 15;
  const int akoff = 16 * (lane >> 4);
  const int swz   = (arow & 7) << 4;

  f32x4 cacc = {0.f, 0.f, 0.f, 0.f};
#pragma unroll
  for (int ts = 0; ts < 2; ++ts) {
    bf16x8 a = *(bf16x8*)((char*)cact + arow * 128 + ((64 * ts + akoff) ^ swz));
    cacc = __builtin_amdgcn_mfma_f32_16x16x32_bf16(a, bfc[ts], cacc, 0, 0, 0);
  }

  f32x4 rmax;
  rmax[0] = rmax[1] = rmax[2] = rmax[3] = -__builtin_inff();
#pragma unroll
  for (int s = 0; s < S_; ++s) {
    f32x4 acc = {0.f, 0.f, 0.f, 0.f};
#pragma unroll
    for (int ts = 0; ts < 2; ++ts) {
      bf16x8 a = *(bf16x8*)((char*)dact + (s * 16 + arow) * 128 + ((64 * ts + akoff) ^ swz));
      acc = __builtin_amdgcn_mfma_f32_16x16x32_bf16(a, bfd[ts], acc, 0, 0, 0);
    }
#pragma unroll
    for (int i = 0; i < 4; ++i) rmax[i] = fmaxf(rmax[i], acc[i]);
  }

  { // stage: C/D mapping col=lane&15, row=4*(lane>>4)+i
    const int ol = lane & 15;
    const int rb = 4 * (lane >> 4);
#pragma unroll
    for (int i = 0; i < 4; ++i) ost[rb + i][16 * w + ol] = rmax[i] + cacc[i];
  }
  __syncthreads();
  { // coalesced store: out[b][o][n0..n0+15]
    const int o  = t >> 2;
    const int sg = t & 3;
    f32x4 v;
#pragma unroll
    for (int i = 0; i < 4; ++i) v[i] = ost[sg * 4 + i][o];
    *(f32x4*)&out[((size_t)(b * OUT_ + o)) * N_ + n0 + sg * 4] = v;
  }
}

extern "C" void kernel_launch(void* const* d_in, const int* in_sizes, int n_in,
                              void* d_out, int out_size, void* d_ws, size_t ws_size,
                              hipStream_t stream) {
  const float* x      = (const float*)d_in[0];
  const int*   cif    = (const int*)  d_in[1];
  const float* scores = (const float*)d_in[2];
  const float* dww    = (const float*)d_in[3];
  const float* pw     = (const float*)d_in[4];
  const float* gamma  = (const float*)d_in[5];
  const float* beta   = (const float*)d_in[6];
  float* out = (float*)d_out;

  char* ws = (char*)d_ws;
  __bf16* xt     = (__bf16*)(ws);                                 //  8,388,608 B
  int*    sampled= (int*)   (ws + 8388608);                       //  2,621,440 B
  float*  stats  = (float*) (ws + 8388608 + 2621440);             //      1,024 B
  float*  AB     = (float*) (ws + 8388608 + 2621440 + 1024);      //      1,024 B

  hipMemsetAsync(stats, 0, 256 * sizeof(float), stream);

  dim3 tb(32, 8);
  dim3 tg(N_ / 32, C_ / 32, B_);
  k_transpose<<<tg, tb, 0, stream>>>(x, xt);
  k_sample<<<ROWS_ / 256, 256, 0, stream>>>(scores, cif, sampled);
  k_stats<<<1024, 256, 0, stream>>>((const unsigned int*)xt, sampled, stats);
  k_finalize<<<1, 128, 0, stream>>>(stats, dww, gamma, beta, AB);
  k_main<<<ROWS_ / 16, 256, 0, stream>>>(xt, sampled, AB, pw, out);
}